// Round 13
// baseline (2921.323 us; speedup 1.0000x reference)
//
#include <hip/hip_runtime.h>

#define TT 2048
#define BB 128
#define DD 128
#define HH 256

typedef float f32x4 __attribute__((ext_vector_type(4)));
typedef _Float16 f16x8 __attribute__((ext_vector_type(8)));
typedef _Float16 f16x4 __attribute__((ext_vector_type(4)));

// LDS-visibility barrier WITHOUT scheduling walls: drain lgkmcnt (so our
// ds_writes are visible) then s_barrier. The backend never moves DS ops
// across s_barrier, so correctness holds; VALU/MFMA/address work may now
// legally cross the barrier, letting the scheduler overlap step boundaries.
static __device__ __forceinline__ void lds_barrier() {
    asm volatile("s_waitcnt lgkmcnt(0)" ::: "memory");
    __builtin_amdgcn_s_barrier();
}

// ---------------------------------------------------------------------------
// xproj (unchanged, ~97 us)
// ---------------------------------------------------------------------------
__global__ __launch_bounds__(256, 2) void xproj_mfma(
    const float* __restrict__ x, const float* __restrict__ W_in,
    const float* __restrict__ b_in, const float* __restrict__ b_h,
    float* __restrict__ out)
{
    __shared__ short xs[64 * 128];
    const int tid  = threadIdx.x;
    const int lane = tid & 63;
    const int w    = tid >> 6;
    const int lrow = lane & 15;
    const int lgrp = lane >> 4;
    const long rbase = (long)blockIdx.x * 64;

    f16x8 bw[4][4];
    #pragma unroll
    for (int kc = 0; kc < 4; ++kc)
        #pragma unroll
        for (int nt = 0; nt < 4; ++nt) {
            const int n = w * 64 + nt * 16 + lrow;
            #pragma unroll
            for (int i = 0; i < 8; ++i)
                bw[kc][nt][i] = (_Float16)W_in[(kc * 32 + lgrp * 8 + i) * HH + n];
        }
    float bias[4];
    #pragma unroll
    for (int nt = 0; nt < 4; ++nt) {
        const int n = w * 64 + nt * 16 + lrow;
        bias[nt] = b_in[n] + b_h[n];
    }
    {
        const float4* xg = (const float4*)(x + rbase * DD);
        #pragma unroll
        for (int th = 0; th < 8; ++th) {
            int idx = tid + th * 256;
            int r   = idx >> 5;
            int c4  = idx & 31;
            float4 v = xg[idx];
            f16x4 p;
            p[0] = (_Float16)v.x; p[1] = (_Float16)v.y;
            p[2] = (_Float16)v.z; p[3] = (_Float16)v.w;
            unsigned off = (unsigned)(r * 256 + c4 * 8);
            off ^= (unsigned)((r & 7) << 4);
            *(f16x4*)((char*)xs + off) = p;
        }
    }
    __syncthreads();

    #pragma unroll
    for (int mt = 0; mt < 4; ++mt) {
        const int r = mt * 16 + lrow;
        f16x8 a[4];
        #pragma unroll
        for (int kc = 0; kc < 4; ++kc) {
            unsigned off = (unsigned)(r * 256 + kc * 64 + lgrp * 16);
            off ^= (unsigned)((r & 7) << 4);
            a[kc] = *(const f16x8*)((const char*)xs + off);
        }
        f32x4 acc[4];
        #pragma unroll
        for (int nt = 0; nt < 4; ++nt) { f32x4 c = {bias[nt], bias[nt], bias[nt], bias[nt]}; acc[nt] = c; }
        #pragma unroll
        for (int kc = 0; kc < 4; ++kc)
            #pragma unroll
            for (int nt = 0; nt < 4; ++nt)
                acc[nt] = __builtin_amdgcn_mfma_f32_16x16x32_f16(a[kc], bw[kc][nt], acc[nt], 0, 0, 0);
        #pragma unroll
        for (int nt = 0; nt < 4; ++nt)
            #pragma unroll
            for (int rr = 0; rr < 4; ++rr)
                out[(rbase + mt * 16 + lgrp * 4 + rr) * HH + w * 64 + nt * 16 + lrow] = acc[nt][rr];
    }
}

// ---------------------------------------------------------------------------
// Recurrence: r9 structure (8 WGs x 16 rows, 4 waves, 64 j-cols/wave, W_h^T
// in VGPR/AGPR, h f16 in swizzled LDS dbuf, xp prefetch distance 2) with:
//  - barrier without sched walls (legal cross-boundary scheduling),
//  - round-robin chains kc=0..6 (short MFMA critical path, r12 lesson),
//  - STAGGERED finish: per-chain kc=7 with epilogues interleaved between the
//    remaining chains' final MFMAs, so tanh VALU overlaps MFMA pipe drain.
// ---------------------------------------------------------------------------
template<int MT>
static __device__ __forceinline__ void rec_epi(
    const f32x4& a, float* pst, short* nxtb, int lrow, int lgrp, int jb)
{
    f32x4 hv;
    #pragma unroll
    for (int rr = 0; rr < 4; ++rr) {
        // tanh(s) = 1 - 2/(exp(2s)+1); saturates correctly at +-inf
        float e = __expf(2.0f * a[rr]);
        hv[rr] = __builtin_fmaf(-2.0f, __builtin_amdgcn_rcpf(e + 1.0f), 1.0f);
    }
    *(f32x4*)(pst + MT * 16) = hv;   // global h store, fire & forget
    f16x4 q;
    #pragma unroll
    for (int rr = 0; rr < 4; ++rr) q[rr] = (_Float16)hv[rr];
    // D mapping: col g = lane&15 (batch row), row j = jb + MT*16 + lgrp*4 + rr
    unsigned off = (unsigned)(lrow * 512 + (jb + MT * 16 + lgrp * 4) * 2)
                 ^ ((unsigned)(lrow & 7) << 4);
    *(f16x4*)((char*)nxtb + off) = q;
}

template<bool PF>
static __device__ __forceinline__ void rec_step(
    const float* pld, float* pst,
    f32x4 (&xp)[4],                  // in: C-init for this step; out (PF): t+2
    const short* curb, short* nxtb,
    const f16x8 (&wh)[4][8], int lrow, int lgrp, int jb)
{
    // B-frags: h[g = lane&15][k = kc*32 + lgrp*8 + i] from swizzled LDS
    f16x8 bbf[8];
    #pragma unroll
    for (int kc = 0; kc < 8; ++kc) {
        unsigned off = (unsigned)(lrow * 512 + kc * 64 + lgrp * 16)
                     ^ ((unsigned)(lrow & 7) << 4);
        bbf[kc] = *(const f16x8*)((const char*)curb + off);
    }

    f32x4 acc[4];
    #pragma unroll
    for (int mt = 0; mt < 4; ++mt) acc[mt] = xp[mt];
    if (PF) {   // anti-dep: issues early, consumed 2 steps later
        #pragma unroll
        for (int mt = 0; mt < 4; ++mt)
            xp[mt] = *(const f32x4*)(pld + mt * 16);
    }

    // main MFMA region: kc = 0..6 round-robin over the 4 independent chains
    #pragma unroll
    for (int kc = 0; kc < 7; ++kc)
        #pragma unroll
        for (int mt = 0; mt < 4; ++mt)
            acc[mt] = __builtin_amdgcn_mfma_f32_16x16x32_f16(wh[mt][kc], bbf[kc], acc[mt], 0, 0, 0);

    // staggered finish: chain mt's last MFMA, epilogues interleaved so tanh
    // VALU of finished chains overlaps the remaining chains' MFMA drain
    acc[0] = __builtin_amdgcn_mfma_f32_16x16x32_f16(wh[0][7], bbf[7], acc[0], 0, 0, 0);
    acc[1] = __builtin_amdgcn_mfma_f32_16x16x32_f16(wh[1][7], bbf[7], acc[1], 0, 0, 0);
    rec_epi<0>(acc[0], pst, nxtb, lrow, lgrp, jb);
    acc[2] = __builtin_amdgcn_mfma_f32_16x16x32_f16(wh[2][7], bbf[7], acc[2], 0, 0, 0);
    rec_epi<1>(acc[1], pst, nxtb, lrow, lgrp, jb);
    acc[3] = __builtin_amdgcn_mfma_f32_16x16x32_f16(wh[3][7], bbf[7], acc[3], 0, 0, 0);
    rec_epi<2>(acc[2], pst, nxtb, lrow, lgrp, jb);
    rec_epi<3>(acc[3], pst, nxtb, lrow, lgrp, jb);

    lds_barrier();
}

__global__ __launch_bounds__(256, 1) void rnn_rec_mfma(
    const float* __restrict__ h0, const float* __restrict__ W_h, float* io)
{
    __shared__ short hb0[16 * 256];  // f16 swizzled h, buffer 0 (8 KB)
    __shared__ short hb1[16 * 256];  // buffer 1
    const int tid  = threadIdx.x;
    const int lane = tid & 63;
    const int w    = tid >> 6;       // 0..3
    const int lrow = lane & 15;
    const int lgrp = lane >> 4;
    const int b0   = blockIdx.x * 16;
    const int jb   = w * 64;

    // A-frags: A[j][k] = W_h[k][j], j = jb + mt*16 + lrow, k = kc*32 + lgrp*8 + i
    f16x8 wh[4][8];
    #pragma unroll
    for (int mt = 0; mt < 4; ++mt) {
        const int j = jb + mt * 16 + lrow;
        #pragma unroll
        for (int kc = 0; kc < 8; ++kc)
            #pragma unroll
            for (int i = 0; i < 8; ++i)
                wh[mt][kc][i] = (_Float16)W_h[(kc * 32 + lgrp * 8 + i) * HH + j];
    }

    // h_lds[0] <- h0 (fp32 -> f16, swizzled [g][k])
    {
        const int g  = tid >> 4;            // 0..15
        const int k0 = (tid & 15) * 16;     // 16 f16 per thread
        const float* hp = h0 + (b0 + g) * HH + k0;
        #pragma unroll
        for (int cc = 0; cc < 2; ++cc) {
            f16x8 p;
            #pragma unroll
            for (int i = 0; i < 8; ++i) p[i] = (_Float16)hp[cc * 8 + i];
            unsigned off = (unsigned)(g * 512 + k0 * 2 + cc * 16);
            off ^= (unsigned)((g & 7) << 4);
            *(f16x8*)((char*)hb0 + off) = p;
        }
    }

    // running pointers (strength-reduced)
    const long S = (long)BB * HH;
    const long base = (long)(b0 + lrow) * HH + jb + lgrp * 4;
    const float* pld = io + base + 2 * S;     // prefetch t+2
    float*       pst = io + base;             // store t

    // xp preload (C-init) for t=0 / t=1 (distance-2 parity registers)
    f32x4 xa[4], xb[4];
    #pragma unroll
    for (int mt = 0; mt < 4; ++mt) {
        xa[mt] = *(const f32x4*)(io + base + 0 * S + mt * 16);
        xb[mt] = *(const f32x4*)(io + base + 1 * S + mt * 16);
    }
    __syncthreads();

    for (int t = 0; t < TT - 2; t += 2) {
        rec_step<true>(pld, pst, xa, hb0, hb1, wh, lrow, lgrp, jb);
        pld += S; pst += S;
        rec_step<true>(pld, pst, xb, hb1, hb0, wh, lrow, lgrp, jb);
        pld += S; pst += S;
    }
    // peeled final two steps: no prefetch loads (no OOB, no alias clamp)
    rec_step<false>(pld, pst, xa, hb0, hb1, wh, lrow, lgrp, jb);
    pst += S;
    rec_step<false>(pld, pst, xb, hb1, hb0, wh, lrow, lgrp, jb);
}

extern "C" void kernel_launch(void* const* d_in, const int* in_sizes, int n_in,
                              void* d_out, int out_size, void* d_ws, size_t ws_size,
                              hipStream_t stream) {
    const float* x    = (const float*)d_in[0];
    const float* h0   = (const float*)d_in[1];
    const float* W_in = (const float*)d_in[2];
    const float* b_in = (const float*)d_in[3];
    const float* W_h  = (const float*)d_in[4];
    const float* b_h  = (const float*)d_in[5];
    float* out = (float*)d_out;

    xproj_mfma<<<(TT * BB) / 64, 256, 0, stream>>>(x, W_in, b_in, b_h, out);
    rnn_rec_mfma<<<BB / 16, 256, 0, stream>>>(h0, W_h, out);
}